// Round 10
// baseline (67.121 us; speedup 1.0000x reference)
//
#include <hip/hip_runtime.h>

#define BB 16
#define QQ 64
#define KK 512
#define DD 256
#define HH 256
#define KTILE 128
#define NZ 4

#define LOG2E2 2.88539008177792681f   // 2*log2(e): exp2(LOG2E2*x) = e^{2x}

typedef unsigned int uint;
typedef unsigned short ushort;

__device__ __forceinline__ float fast_exp2(float x) {
#if __has_builtin(__builtin_amdgcn_exp2f)
    return __builtin_amdgcn_exp2f(x);
#else
    return exp2f(x);
#endif
}

__device__ __forceinline__ ushort f32_to_bf16_rtne(float x) {
    uint u = __float_as_uint(x);
    u = (u + 0x7FFFu + ((u >> 16) & 1u)) >> 16;
    return (ushort)u;
}

// unpack 8 bf16 (uint4) -> two float4
__device__ __forceinline__ void cvt8(uint4 u, float4& a, float4& b) {
    a.x = __uint_as_float(u.x << 16); a.y = __uint_as_float(u.x & 0xFFFF0000u);
    a.z = __uint_as_float(u.y << 16); a.w = __uint_as_float(u.y & 0xFFFF0000u);
    b.x = __uint_as_float(u.z << 16); b.y = __uint_as_float(u.z & 0xFFFF0000u);
    b.z = __uint_as_float(u.w << 16); b.w = __uint_as_float(u.w & 0xFFFF0000u);
}

// unpack 4 bf16 (uint2) -> float4
__device__ __forceinline__ float4 cvt4(uint2 u) {
    float4 a;
    a.x = __uint_as_float(u.x << 16); a.y = __uint_as_float(u.x & 0xFFFF0000u);
    a.z = __uint_as_float(u.y << 16); a.w = __uint_as_float(u.y & 0xFFFF0000u);
    return a;
}

// ---------------------------------------------------------------------------
// Projections + V bf16 conversion, one launch.
//  rt <  16 : query proj  -> f32 qf (pre-scaled by 2log2e)
//  rt <  144: key proj    -> bf16 kfeat (pre-scaled); masked tiles skipped
//  rt < 176 : V f32->bf16 (y==0 only); masked rows skipped
// ---------------------------------------------------------------------------
__global__ __launch_bounds__(256) void proj_both(
        const float* __restrict__ Xq, const float* __restrict__ Wq, float* __restrict__ Yq,
        const float* __restrict__ Xk, const float* __restrict__ Wk, ushort* __restrict__ Yk16,
        const float* __restrict__ Xv, ushort* __restrict__ Yv16,
        const int* __restrict__ valid_lens) {
    const int rt  = blockIdx.x;
    const int tid = threadIdx.x;

    if (rt >= 144) {            // ---- V convert ----
        if (blockIdx.y != 0) return;
        const int s    = rt - 144;        // 0..31, 2 slices per batch
        const int bb   = s >> 1;
        const int row0 = (s & 1) * 256;
        int rows = valid_lens[bb] - row0;
        rows = (rows < 0) ? 0 : ((rows > 256) ? 256 : rows);
        const int count = rows * DD;
        const float* src = Xv + ((size_t)bb * KK + row0) * DD;
        ushort* dst = Yv16 + ((size_t)bb * KK + row0) * DD;
        for (int i = tid * 4; i < count; i += 1024) {
            float4 v = *(const float4*)(src + i);
            ushort4 o;
            o.x = f32_to_bf16_rtne(v.x); o.y = f32_to_bf16_rtne(v.y);
            o.z = f32_to_bf16_rtne(v.z); o.w = f32_to_bf16_rtne(v.w);
            *(ushort4*)(dst + i) = o;
        }
        return;
    }

    __shared__ float XsT[32][68];
    __shared__ float Ws[32][64];
    const bool is_q = (rt < 16);
    const float* X; const float* W; int row0;
    if (is_q) { X = Xq; W = Wq; row0 = rt * 64; }
    else {
        X = Xk; W = Wk; row0 = (rt - 16) * 64;
        const int bb    = row0 >> 9;
        const int local = row0 & 511;
        if (local >= valid_lens[bb]) return;
    }
    const int col0 = blockIdx.y * 64;
    const int tx = tid & 15, ty = tid >> 4;

    float acc[4][4] = {};

    for (int k0 = 0; k0 < HH; k0 += 32) {
        {
            const int m  = tid >> 3;
            const int kk = (tid & 7) * 4;
            #pragma unroll
            for (int s = 0; s < 2; ++s) {
                float4 x4 = *(const float4*)(X + (size_t)(row0 + m + 32*s) * HH + k0 + kk);
                XsT[kk+0][m+32*s] = x4.x;
                XsT[kk+1][m+32*s] = x4.y;
                XsT[kk+2][m+32*s] = x4.z;
                XsT[kk+3][m+32*s] = x4.w;
            }
        }
        {
            const int kk = tid >> 4;
            const int c  = (tid & 15) * 4;
            #pragma unroll
            for (int s = 0; s < 2; ++s) {
                float4 w4 = *(const float4*)(W + (size_t)(k0 + kk + 16*s) * HH + col0 + c);
                *(float4*)(&Ws[kk+16*s][c]) = w4;
            }
        }
        __syncthreads();
        #pragma unroll
        for (int kk = 0; kk < 32; ++kk) {
            float4 a = *(const float4*)(&XsT[kk][ty*4]);
            float4 b = *(const float4*)(&Ws[kk][tx*4]);
            acc[0][0] += a.x*b.x; acc[0][1] += a.x*b.y; acc[0][2] += a.x*b.z; acc[0][3] += a.x*b.w;
            acc[1][0] += a.y*b.x; acc[1][1] += a.y*b.y; acc[1][2] += a.y*b.z; acc[1][3] += a.y*b.w;
            acc[2][0] += a.z*b.x; acc[2][1] += a.z*b.y; acc[2][2] += a.z*b.z; acc[2][3] += a.z*b.w;
            acc[3][0] += a.w*b.x; acc[3][1] += a.w*b.y; acc[3][2] += a.w*b.z; acc[3][3] += a.w*b.w;
        }
        __syncthreads();
    }
    if (is_q) {
        #pragma unroll
        for (int i = 0; i < 4; ++i) {
            float4 o = make_float4(acc[i][0]*LOG2E2, acc[i][1]*LOG2E2,
                                   acc[i][2]*LOG2E2, acc[i][3]*LOG2E2);
            *(float4*)(Yq + (size_t)(row0 + ty*4 + i) * HH + col0 + tx*4) = o;
        }
    } else {
        #pragma unroll
        for (int i = 0; i < 4; ++i) {
            ushort4 o;
            o.x = f32_to_bf16_rtne(acc[i][0]*LOG2E2);
            o.y = f32_to_bf16_rtne(acc[i][1]*LOG2E2);
            o.z = f32_to_bf16_rtne(acc[i][2]*LOG2E2);
            o.w = f32_to_bf16_rtne(acc[i][3]*LOG2E2);
            *(ushort4*)(Yk16 + (size_t)(row0 + ty*4 + i) * HH + col0 + tx*4) = o;
        }
    }
}

// ---------------------------------------------------------------------------
// Flash-style fused kernel, q-pair items. Grid = 2048 static = (b, z, qpair);
// inactive tiles exit. 512 thr (8 waves): Phase A wave strips = 16 k, both q
// (K amortized 2x); Phase B single wave per q-row; Phase C same strips, V
// bf16 (traffic halved), both q per V load. XCD-swizzled block ids.
// ---------------------------------------------------------------------------
__global__ __launch_bounds__(512) void fused_flash(
        const float* __restrict__ qf, const ushort* __restrict__ kf16,
        const float* __restrict__ w_v, const int* __restrict__ valid_lens,
        const ushort* __restrict__ v16,
        float* __restrict__ pm, float* __restrict__ pl, float* __restrict__ po) {
    __shared__ float sc[2][KTILE];      // 1 KB scores
    __shared__ float pp[2][KTILE];      // 1 KB unnormalized probs
    __shared__ float red[8][2][DD];     // 16 KB PV partials

    const int orig = blockIdx.x;
    const int wg   = (orig & 7) * 256 + (orig >> 3);   // bijective XCD swizzle
    const int b    = wg >> 7;
    const int r    = wg & 127;
    const int z    = r >> 5;
    const int q0   = (r & 31) * 2;

    const int vl      = valid_lens[b];
    const int tile_lo = z * KTILE;
    if (tile_lo >= vl) return;
    const int tile_hi = (tile_lo + KTILE < vl) ? (tile_lo + KTILE) : vl;

    const int tid  = threadIdx.x;
    const int lane = tid & 63;
    const int w    = tid >> 6;          // 0..7
    const int hg   = lane & 15;
    const int ksub = lane >> 4;
    const int h0   = hg * 16;

    if (tid < 2 * KTILE) sc[tid >> 7][tid & 127] = -1e6f;

    float4 nw[4];
    float wvsum = 0.f;
    #pragma unroll
    for (int i = 0; i < 4; ++i) {
        float4 wv4 = *(const float4*)(w_v + h0 + i*4);
        wvsum += ((wv4.x + wv4.y) + (wv4.z + wv4.w));
        nw[i] = make_float4(-2.f*wv4.x, -2.f*wv4.y, -2.f*wv4.z, -2.f*wv4.w);
    }
    float4 qA[4], qB[4];
    {
        const float* qrA = qf + (size_t)(b*QQ + q0) * HH + h0;
        const float* qrB = qrA + HH;
        #pragma unroll
        for (int i = 0; i < 4; ++i) {
            qA[i] = *(const float4*)(qrA + i*4);
            qB[i] = *(const float4*)(qrB + i*4);
        }
    }

    // wave strip: 16 k
    const int lo  = tile_lo + w * 16;
    int hi = lo + 16; hi = (hi > tile_hi) ? tile_hi : hi;
    const int cnt = hi - lo;
    const int ng  = (cnt <= 0) ? 0 : ((cnt + 3) >> 2);

    __syncthreads();   // sc init visible

    // ---- Phase A: scores for both q over the strip ----
    {
        const size_t brows = (size_t)b * KK;
        uint4 c0, c1;
        if (ng > 0) {
            int row = lo + ksub;
            row = (row < tile_hi) ? row : (tile_hi - 1);
            const ushort* p = kf16 + (brows + row) * HH + h0;
            c0 = *(const uint4*)(p);
            c1 = *(const uint4*)(p + 8);
        }
        for (int g = 0; g < ng; ++g) {
            uint4 n0, n1;
            const bool more = (g + 1 < ng);
            if (more) {
                int row = lo + (g+1)*4 + ksub;
                row = (row < tile_hi) ? row : (tile_hi - 1);
                const ushort* p = kf16 + (brows + row) * HH + h0;
                n0 = *(const uint4*)(p);
                n1 = *(const uint4*)(p + 8);
            }
            float4 kv[4];
            cvt8(c0, kv[0], kv[1]);
            cvt8(c1, kv[2], kv[3]);

            float a0 = wvsum, a1 = 0.f, a2 = 0.f, a3 = 0.f;
            float b0 = wvsum, b1 = 0.f, b2 = 0.f, b3 = 0.f;
            #pragma unroll
            for (int i = 0; i < 4; ++i) {
                float eA0 = fast_exp2(qA[i].x + kv[i].x);
                float eA1 = fast_exp2(qA[i].y + kv[i].y);
                float eA2 = fast_exp2(qA[i].z + kv[i].z);
                float eA3 = fast_exp2(qA[i].w + kv[i].w);
                a0 = fmaf(nw[i].x, __builtin_amdgcn_rcpf(eA0 + 1.f), a0);
                a1 = fmaf(nw[i].y, __builtin_amdgcn_rcpf(eA1 + 1.f), a1);
                a2 = fmaf(nw[i].z, __builtin_amdgcn_rcpf(eA2 + 1.f), a2);
                a3 = fmaf(nw[i].w, __builtin_amdgcn_rcpf(eA3 + 1.f), a3);
                float eB0 = fast_exp2(qB[i].x + kv[i].x);
                float eB1 = fast_exp2(qB[i].y + kv[i].y);
                float eB2 = fast_exp2(qB[i].z + kv[i].z);
                float eB3 = fast_exp2(qB[i].w + kv[i].w);
                b0 = fmaf(nw[i].x, __builtin_amdgcn_rcpf(eB0 + 1.f), b0);
                b1 = fmaf(nw[i].y, __builtin_amdgcn_rcpf(eB1 + 1.f), b1);
                b2 = fmaf(nw[i].z, __builtin_amdgcn_rcpf(eB2 + 1.f), b2);
                b3 = fmaf(nw[i].w, __builtin_amdgcn_rcpf(eB3 + 1.f), b3);
            }
            float sA = (a0 + a1) + (a2 + a3);
            float sB = (b0 + b1) + (b2 + b3);
            #pragma unroll
            for (int off = 8; off; off >>= 1) {
                sA += __shfl_xor(sA, off);
                sB += __shfl_xor(sB, off);
            }
            const int k = lo + g*4 + ksub;
            if (hg == 0 && k < hi) {
                sc[0][k - tile_lo] = sA;
                sc[1][k - tile_lo] = sB;
            }
            if (more) { c0 = n0; c1 = n1; }
        }
    }
    __syncthreads();

    // ---- Phase B: per-row tile max/sum + unnormalized p (waves 0,1) ----
    if (w < 2) {
        float s0 = sc[w][lane*2], s1 = sc[w][lane*2 + 1];
        float m = fmaxf(s0, s1);
        #pragma unroll
        for (int off = 32; off; off >>= 1) m = fmaxf(m, __shfl_xor(m, off));
        float p0 = __expf(s0 - m), p1 = __expf(s1 - m);
        float l = p0 + p1;
        #pragma unroll
        for (int off = 32; off; off >>= 1) l += __shfl_xor(l, off);
        pp[w][lane*2]     = p0;
        pp[w][lane*2 + 1] = p1;
        if (lane == 0) {
            const int id = ((b*QQ + q0 + w) << 2) + z;
            pm[id] = m; pl[id] = l;
        }
    }
    __syncthreads();

    // ---- Phase C: PV partial over the strip, bf16 V, both q ----
    {
        const ushort* V = v16 + (size_t)b * KK * DD + lane*4;
        float4 aA = make_float4(0.f,0.f,0.f,0.f);
        float4 aB = aA;
        #pragma unroll 4
        for (int k = lo; k < hi; ++k) {
            const float pA = pp[0][k - tile_lo];
            const float pB = pp[1][k - tile_lo];
            uint2 u = *(const uint2*)(V + (size_t)k * DD);
            float4 v4 = cvt4(u);
            aA.x = fmaf(pA, v4.x, aA.x); aA.y = fmaf(pA, v4.y, aA.y);
            aA.z = fmaf(pA, v4.z, aA.z); aA.w = fmaf(pA, v4.w, aA.w);
            aB.x = fmaf(pB, v4.x, aB.x); aB.y = fmaf(pB, v4.y, aB.y);
            aB.z = fmaf(pB, v4.z, aB.z); aB.w = fmaf(pB, v4.w, aB.w);
        }
        *(float4*)(&red[w][0][lane*4]) = aA;
        *(float4*)(&red[w][1][lane*4]) = aB;
    }
    __syncthreads();

    // ---- write PV partials: 512 thr = 2 q x 256 d ----
    {
        const int qq = tid >> 8, d = tid & 255;
        float o = 0.f;
        #pragma unroll
        for (int ww = 0; ww < 8; ++ww) o += red[ww][qq][d];
        po[(size_t)(((b*QQ + q0 + qq) << 2) + z) * DD + d] = o;
    }
}

// ---------------------------------------------------------------------------
// Combine <=4 tile partials per (b,q): online-softmax merge. grid (B,Q), 256.
// ---------------------------------------------------------------------------
__global__ __launch_bounds__(256) void combine_kernel(
        const float* __restrict__ pm, const float* __restrict__ pl,
        const float* __restrict__ po, const int* __restrict__ valid_lens,
        float* __restrict__ out) {
    const int b   = blockIdx.x;
    const int q   = blockIdx.y;
    const int tid = threadIdx.x;
    const int vl  = valid_lens[b];
    const int nz  = (vl + KTILE - 1) >> 7;
    const int idx4 = (b*QQ + q) << 2;

    float mz[NZ], wz[NZ];
    float M = -3.0e38f;
    #pragma unroll
    for (int z = 0; z < NZ; ++z) {
        mz[z] = (z < nz) ? pm[idx4 + z] : -3.0e38f;
        M = fmaxf(M, mz[z]);
    }
    float L = 0.f;
    #pragma unroll
    for (int z = 0; z < NZ; ++z) {
        wz[z] = (z < nz) ? __expf(mz[z] - M) : 0.f;
        L = fmaf(wz[z], (z < nz) ? pl[idx4 + z] : 0.f, L);
    }
    const float inv = 1.f / L;

    float o = 0.f;
    #pragma unroll
    for (int z = 0; z < NZ; ++z) {
        if (z < nz)
            o = fmaf(wz[z], po[(size_t)(idx4 + z) * DD + tid], o);
    }
    out[(size_t)(b*QQ + q) * DD + tid] = o * inv;
}

extern "C" void kernel_launch(void* const* d_in, const int* in_sizes, int n_in,
                              void* d_out, int out_size, void* d_ws, size_t ws_size,
                              hipStream_t stream) {
    (void)in_sizes; (void)n_in; (void)out_size; (void)ws_size;
    const float* querys     = (const float*)d_in[0];
    const float* keys       = (const float*)d_in[1];
    const float* values     = (const float*)d_in[2];
    const int*   valid_lens = (const int*)d_in[3];
    const float* Wq         = (const float*)d_in[4];
    const float* Wk         = (const float*)d_in[5];
    const float* w_v        = (const float*)d_in[6];
    float* out = (float*)d_out;

    float*  qf    = (float*)d_ws;                          // 1 MB f32 (pre-scaled)
    ushort* kfeat = (ushort*)(qf + (size_t)BB*QQ*HH);      // 4 MB bf16 (pre-scaled)
    ushort* v16   = kfeat + (size_t)BB*KK*HH;              // 4 MB bf16 values
    float*  pm    = (float*)(v16 + (size_t)BB*KK*DD);      // 16 KB
    float*  pl    = pm + BB*QQ*NZ;                         // 16 KB
    float*  po    = pl + BB*QQ*NZ;                         // 4 MB

    proj_both<<<dim3(176, HH/64), 256, 0, stream>>>(
        querys, Wq, qf, keys, Wk, kfeat, values, v16, valid_lens);
    fused_flash<<<dim3(BB*NZ*32), 512, 0, stream>>>(
        qf, kfeat, w_v, valid_lens, v16, pm, pl, po);
    combine_kernel<<<dim3(BB, QQ), 256, 0, stream>>>(
        pm, pl, po, valid_lens, out);
}

// Round 11
// 61.957 us; speedup vs baseline: 1.0833x; 1.0833x over previous
//
#include <hip/hip_runtime.h>

#define BB 16
#define QQ 64
#define KK 512
#define DD 256
#define HH 256
#define KTILE 128
#define NZ 4
#define PERSIST 1024

#define LOG2E2 2.88539008177792681f   // 2*log2(e): exp2(LOG2E2*x) = e^{2x}

typedef unsigned int uint;
typedef unsigned short ushort;

__device__ __forceinline__ float fast_exp2(float x) {
#if __has_builtin(__builtin_amdgcn_exp2f)
    return __builtin_amdgcn_exp2f(x);
#else
    return exp2f(x);
#endif
}

__device__ __forceinline__ ushort f32_to_bf16_rtne(float x) {
    uint u = __float_as_uint(x);
    u = (u + 0x7FFFu + ((u >> 16) & 1u)) >> 16;
    return (ushort)u;
}

// unpack 8 bf16 (uint4) -> two float4
__device__ __forceinline__ void cvt8(uint4 u, float4& a, float4& b) {
    a.x = __uint_as_float(u.x << 16); a.y = __uint_as_float(u.x & 0xFFFF0000u);
    a.z = __uint_as_float(u.y << 16); a.w = __uint_as_float(u.y & 0xFFFF0000u);
    b.x = __uint_as_float(u.z << 16); b.y = __uint_as_float(u.z & 0xFFFF0000u);
    b.z = __uint_as_float(u.w << 16); b.w = __uint_as_float(u.w & 0xFFFF0000u);
}

// unpack 4 bf16 (uint2) -> float4
__device__ __forceinline__ float4 cvt4(uint2 u) {
    float4 a;
    a.x = __uint_as_float(u.x << 16); a.y = __uint_as_float(u.x & 0xFFFF0000u);
    a.z = __uint_as_float(u.y << 16); a.w = __uint_as_float(u.y & 0xFFFF0000u);
    return a;
}

// ---------------------------------------------------------------------------
// Projections + V bf16 conversion, one launch.
//  rt <  16 : query proj  -> f32 qf (pre-scaled by 2log2e)
//  rt <  144: key proj    -> bf16 kfeat (pre-scaled); masked tiles skipped
//  rt < 176 : V f32->bf16 (y==0 only); masked rows skipped
// ---------------------------------------------------------------------------
__global__ __launch_bounds__(256) void proj_both(
        const float* __restrict__ Xq, const float* __restrict__ Wq, float* __restrict__ Yq,
        const float* __restrict__ Xk, const float* __restrict__ Wk, ushort* __restrict__ Yk16,
        const float* __restrict__ Xv, ushort* __restrict__ Yv16,
        const int* __restrict__ valid_lens) {
    const int rt  = blockIdx.x;
    const int tid = threadIdx.x;

    if (rt >= 144) {            // ---- V convert ----
        if (blockIdx.y != 0) return;
        const int s    = rt - 144;        // 0..31, 2 slices per batch
        const int bb   = s >> 1;
        const int row0 = (s & 1) * 256;
        int rows = valid_lens[bb] - row0;
        rows = (rows < 0) ? 0 : ((rows > 256) ? 256 : rows);
        const int count = rows * DD;
        const float* src = Xv + ((size_t)bb * KK + row0) * DD;
        ushort* dst = Yv16 + ((size_t)bb * KK + row0) * DD;
        for (int i = tid * 4; i < count; i += 1024) {
            float4 v = *(const float4*)(src + i);
            ushort4 o;
            o.x = f32_to_bf16_rtne(v.x); o.y = f32_to_bf16_rtne(v.y);
            o.z = f32_to_bf16_rtne(v.z); o.w = f32_to_bf16_rtne(v.w);
            *(ushort4*)(dst + i) = o;
        }
        return;
    }

    __shared__ float XsT[32][68];
    __shared__ float Ws[32][64];
    const bool is_q = (rt < 16);
    const float* X; const float* W; int row0;
    if (is_q) { X = Xq; W = Wq; row0 = rt * 64; }
    else {
        X = Xk; W = Wk; row0 = (rt - 16) * 64;
        const int bb    = row0 >> 9;
        const int local = row0 & 511;
        if (local >= valid_lens[bb]) return;
    }
    const int col0 = blockIdx.y * 64;
    const int tx = tid & 15, ty = tid >> 4;

    float acc[4][4] = {};

    for (int k0 = 0; k0 < HH; k0 += 32) {
        {
            const int m  = tid >> 3;
            const int kk = (tid & 7) * 4;
            #pragma unroll
            for (int s = 0; s < 2; ++s) {
                float4 x4 = *(const float4*)(X + (size_t)(row0 + m + 32*s) * HH + k0 + kk);
                XsT[kk+0][m+32*s] = x4.x;
                XsT[kk+1][m+32*s] = x4.y;
                XsT[kk+2][m+32*s] = x4.z;
                XsT[kk+3][m+32*s] = x4.w;
            }
        }
        {
            const int kk = tid >> 4;
            const int c  = (tid & 15) * 4;
            #pragma unroll
            for (int s = 0; s < 2; ++s) {
                float4 w4 = *(const float4*)(W + (size_t)(k0 + kk + 16*s) * HH + col0 + c);
                *(float4*)(&Ws[kk+16*s][c]) = w4;
            }
        }
        __syncthreads();
        #pragma unroll
        for (int kk = 0; kk < 32; ++kk) {
            float4 a = *(const float4*)(&XsT[kk][ty*4]);
            float4 b = *(const float4*)(&Ws[kk][tx*4]);
            acc[0][0] += a.x*b.x; acc[0][1] += a.x*b.y; acc[0][2] += a.x*b.z; acc[0][3] += a.x*b.w;
            acc[1][0] += a.y*b.x; acc[1][1] += a.y*b.y; acc[1][2] += a.y*b.z; acc[1][3] += a.y*b.w;
            acc[2][0] += a.z*b.x; acc[2][1] += a.z*b.y; acc[2][2] += a.z*b.z; acc[2][3] += a.z*b.w;
            acc[3][0] += a.w*b.x; acc[3][1] += a.w*b.y; acc[3][2] += a.w*b.z; acc[3][3] += a.w*b.w;
        }
        __syncthreads();
    }
    if (is_q) {
        #pragma unroll
        for (int i = 0; i < 4; ++i) {
            float4 o = make_float4(acc[i][0]*LOG2E2, acc[i][1]*LOG2E2,
                                   acc[i][2]*LOG2E2, acc[i][3]*LOG2E2);
            *(float4*)(Yq + (size_t)(row0 + ty*4 + i) * HH + col0 + tx*4) = o;
        }
    } else {
        #pragma unroll
        for (int i = 0; i < 4; ++i) {
            ushort4 o;
            o.x = f32_to_bf16_rtne(acc[i][0]*LOG2E2);
            o.y = f32_to_bf16_rtne(acc[i][1]*LOG2E2);
            o.z = f32_to_bf16_rtne(acc[i][2]*LOG2E2);
            o.w = f32_to_bf16_rtne(acc[i][3]*LOG2E2);
            *(ushort4*)(Yk16 + (size_t)(row0 + ty*4 + i) * HH + col0 + tx*4) = o;
        }
    }
}

// ---------------------------------------------------------------------------
// Persistent flash-style fused kernel, q-pair items. 1024 blocks x 512 thr.
// Work items = (active tile) x 32 q-pairs, enumerated by prefix scan of
// ceil(vl/128); block bid owns a CONTIGUOUS chunk (tail-balanced, same-tile
// items adjacent -> per-XCD L2 reuse of the tile's K/V). Per item: 8 waves x
// 16-k strips compute scores for both q (K loads amortized 2x), per-row
// softmax stats, PV partial with bf16 V (traffic halved, amortized 2x).
// ---------------------------------------------------------------------------
__global__ __launch_bounds__(512) void fused_flash(
        const float* __restrict__ qf, const ushort* __restrict__ kf16,
        const float* __restrict__ w_v, const int* __restrict__ valid_lens,
        const ushort* __restrict__ v16,
        float* __restrict__ pm, float* __restrict__ pl, float* __restrict__ po) {
    __shared__ float sc[2][KTILE];      // 1 KB scores
    __shared__ float pp[2][KTILE];      // 1 KB unnormalized probs
    __shared__ float red[8][2][DD];     // 16 KB PV partials

    const int tid  = threadIdx.x;
    const int lane = tid & 63;
    const int w    = tid >> 6;          // 0..7
    const int hg   = lane & 15;
    const int ksub = lane >> 4;
    const int h0   = hg * 16;

    float4 nw[4];
    float wvsum = 0.f;
    #pragma unroll
    for (int i = 0; i < 4; ++i) {
        float4 wv4 = *(const float4*)(w_v + h0 + i*4);
        wvsum += ((wv4.x + wv4.y) + (wv4.z + wv4.w));
        nw[i] = make_float4(-2.f*wv4.x, -2.f*wv4.y, -2.f*wv4.z, -2.f*wv4.w);
    }

    // total active tiles and this block's contiguous item chunk
    int TT = 0;
    #pragma unroll
    for (int i = 0; i < BB; ++i)
        TT += (valid_lens[i] + KTILE - 1) >> 7;
    const int items = TT * 32;                   // q-pair items
    const int qch   = items >> 10;               // items / 1024
    const int rch   = items & 1023;
    const int bid   = blockIdx.x;
    const int lo_it = bid * qch + ((bid < rch) ? bid : rch);
    const int n_it  = qch + ((bid < rch) ? 1 : 0);

    for (int t = lo_it; t < lo_it + n_it; ++t) {
        const int tile_idx = t >> 5;
        const int q0       = (t & 31) * 2;

        // map tile_idx -> (b, z) via unrolled prefix scan
        int bb = 0, zz = 0, vlb = 1, acc = 0;
        #pragma unroll
        for (int i = 0; i < BB; ++i) {
            const int v   = valid_lens[i];
            const int nzi = (v + KTILE - 1) >> 7;
            const bool hit = (tile_idx >= acc) && (tile_idx < acc + nzi);
            if (hit) { bb = i; zz = tile_idx - acc; vlb = v; }
            acc += nzi;
        }

        const int tile_lo = zz * KTILE;
        const int tile_hi = (tile_lo + KTILE < vlb) ? (tile_lo + KTILE) : vlb;

        if (tid < 2 * KTILE) sc[tid >> 7][tid & 127] = -1e6f;

        float4 qA[4], qB[4];
        {
            const float* qrA = qf + (size_t)(bb*QQ + q0) * HH + h0;
            const float* qrB = qrA + HH;
            #pragma unroll
            for (int i = 0; i < 4; ++i) {
                qA[i] = *(const float4*)(qrA + i*4);
                qB[i] = *(const float4*)(qrB + i*4);
            }
        }

        // wave strip: 16 k
        const int lo  = tile_lo + w * 16;
        int hi = lo + 16; hi = (hi > tile_hi) ? tile_hi : hi;
        const int cnt = hi - lo;
        const int ng  = (cnt <= 0) ? 0 : ((cnt + 3) >> 2);

        __syncthreads();   // sc init visible; prev item consumed

        // ---- Phase A: scores for both q over the strip ----
        {
            const size_t brows = (size_t)bb * KK;
            uint4 c0, c1;
            if (ng > 0) {
                int row = lo + ksub;
                row = (row < tile_hi) ? row : (tile_hi - 1);
                const ushort* p = kf16 + (brows + row) * HH + h0;
                c0 = *(const uint4*)(p);
                c1 = *(const uint4*)(p + 8);
            }
            for (int g = 0; g < ng; ++g) {
                uint4 n0, n1;
                const bool more = (g + 1 < ng);
                if (more) {
                    int row = lo + (g+1)*4 + ksub;
                    row = (row < tile_hi) ? row : (tile_hi - 1);
                    const ushort* p = kf16 + (brows + row) * HH + h0;
                    n0 = *(const uint4*)(p);
                    n1 = *(const uint4*)(p + 8);
                }
                float4 kv[4];
                cvt8(c0, kv[0], kv[1]);
                cvt8(c1, kv[2], kv[3]);

                float a0 = wvsum, a1 = 0.f, a2 = 0.f, a3 = 0.f;
                float b0 = wvsum, b1 = 0.f, b2 = 0.f, b3 = 0.f;
                #pragma unroll
                for (int i = 0; i < 4; ++i) {
                    float eA0 = fast_exp2(qA[i].x + kv[i].x);
                    float eA1 = fast_exp2(qA[i].y + kv[i].y);
                    float eA2 = fast_exp2(qA[i].z + kv[i].z);
                    float eA3 = fast_exp2(qA[i].w + kv[i].w);
                    a0 = fmaf(nw[i].x, __builtin_amdgcn_rcpf(eA0 + 1.f), a0);
                    a1 = fmaf(nw[i].y, __builtin_amdgcn_rcpf(eA1 + 1.f), a1);
                    a2 = fmaf(nw[i].z, __builtin_amdgcn_rcpf(eA2 + 1.f), a2);
                    a3 = fmaf(nw[i].w, __builtin_amdgcn_rcpf(eA3 + 1.f), a3);
                    float eB0 = fast_exp2(qB[i].x + kv[i].x);
                    float eB1 = fast_exp2(qB[i].y + kv[i].y);
                    float eB2 = fast_exp2(qB[i].z + kv[i].z);
                    float eB3 = fast_exp2(qB[i].w + kv[i].w);
                    b0 = fmaf(nw[i].x, __builtin_amdgcn_rcpf(eB0 + 1.f), b0);
                    b1 = fmaf(nw[i].y, __builtin_amdgcn_rcpf(eB1 + 1.f), b1);
                    b2 = fmaf(nw[i].z, __builtin_amdgcn_rcpf(eB2 + 1.f), b2);
                    b3 = fmaf(nw[i].w, __builtin_amdgcn_rcpf(eB3 + 1.f), b3);
                }
                float sA = (a0 + a1) + (a2 + a3);
                float sB = (b0 + b1) + (b2 + b3);
                #pragma unroll
                for (int off = 8; off; off >>= 1) {
                    sA += __shfl_xor(sA, off);
                    sB += __shfl_xor(sB, off);
                }
                const int k = lo + g*4 + ksub;
                if (hg == 0 && k < hi) {
                    sc[0][k - tile_lo] = sA;
                    sc[1][k - tile_lo] = sB;
                }
                if (more) { c0 = n0; c1 = n1; }
            }
        }
        __syncthreads();

        // ---- Phase B: per-row tile max/sum + unnormalized p (waves 0,1) ----
        if (w < 2) {
            float s0 = sc[w][lane*2], s1 = sc[w][lane*2 + 1];
            float m = fmaxf(s0, s1);
            #pragma unroll
            for (int off = 32; off; off >>= 1) m = fmaxf(m, __shfl_xor(m, off));
            float p0 = __expf(s0 - m), p1 = __expf(s1 - m);
            float l = p0 + p1;
            #pragma unroll
            for (int off = 32; off; off >>= 1) l += __shfl_xor(l, off);
            pp[w][lane*2]     = p0;
            pp[w][lane*2 + 1] = p1;
            if (lane == 0) {
                const int id = ((bb*QQ + q0 + w) << 2) + zz;
                pm[id] = m; pl[id] = l;
            }
        }
        __syncthreads();

        // ---- Phase C: PV partial over the strip, bf16 V, both q ----
        {
            const ushort* V = v16 + (size_t)bb * KK * DD + lane*4;
            float4 aA = make_float4(0.f,0.f,0.f,0.f);
            float4 aB = aA;
            #pragma unroll 4
            for (int k = lo; k < hi; ++k) {
                const float pA = pp[0][k - tile_lo];
                const float pB = pp[1][k - tile_lo];
                uint2 u = *(const uint2*)(V + (size_t)k * DD);
                float4 v4 = cvt4(u);
                aA.x = fmaf(pA, v4.x, aA.x); aA.y = fmaf(pA, v4.y, aA.y);
                aA.z = fmaf(pA, v4.z, aA.z); aA.w = fmaf(pA, v4.w, aA.w);
                aB.x = fmaf(pB, v4.x, aB.x); aB.y = fmaf(pB, v4.y, aB.y);
                aB.z = fmaf(pB, v4.z, aB.z); aB.w = fmaf(pB, v4.w, aB.w);
            }
            *(float4*)(&red[w][0][lane*4]) = aA;
            *(float4*)(&red[w][1][lane*4]) = aB;
        }
        __syncthreads();

        // ---- write PV partials: 512 thr = 2 q x 256 d ----
        {
            const int qq = tid >> 8, d = tid & 255;
            float o = 0.f;
            #pragma unroll
            for (int ww = 0; ww < 8; ++ww) o += red[ww][qq][d];
            po[(size_t)(((bb*QQ + q0 + qq) << 2) + zz) * DD + d] = o;
        }
        __syncthreads();
    }
}

// ---------------------------------------------------------------------------
// Combine <=4 tile partials per (b,q): online-softmax merge. grid (B,Q), 256.
// ---------------------------------------------------------------------------
__global__ __launch_bounds__(256) void combine_kernel(
        const float* __restrict__ pm, const float* __restrict__ pl,
        const float* __restrict__ po, const int* __restrict__ valid_lens,
        float* __restrict__ out) {
    const int b   = blockIdx.x;
    const int q   = blockIdx.y;
    const int tid = threadIdx.x;
    const int vl  = valid_lens[b];
    const int nz  = (vl + KTILE - 1) >> 7;
    const int idx4 = (b*QQ + q) << 2;

    float mz[NZ], wz[NZ];
    float M = -3.0e38f;
    #pragma unroll
    for (int z = 0; z < NZ; ++z) {
        mz[z] = (z < nz) ? pm[idx4 + z] : -3.0e38f;
        M = fmaxf(M, mz[z]);
    }
    float L = 0.f;
    #pragma unroll
    for (int z = 0; z < NZ; ++z) {
        wz[z] = (z < nz) ? __expf(mz[z] - M) : 0.f;
        L = fmaf(wz[z], (z < nz) ? pl[idx4 + z] : 0.f, L);
    }
    const float inv = 1.f / L;

    float o = 0.f;
    #pragma unroll
    for (int z = 0; z < NZ; ++z) {
        if (z < nz)
            o = fmaf(wz[z], po[(size_t)(idx4 + z) * DD + tid], o);
    }
    out[(size_t)(b*QQ + q) * DD + tid] = o * inv;
}

extern "C" void kernel_launch(void* const* d_in, const int* in_sizes, int n_in,
                              void* d_out, int out_size, void* d_ws, size_t ws_size,
                              hipStream_t stream) {
    (void)in_sizes; (void)n_in; (void)out_size; (void)ws_size;
    const float* querys     = (const float*)d_in[0];
    const float* keys       = (const float*)d_in[1];
    const float* values     = (const float*)d_in[2];
    const int*   valid_lens = (const int*)d_in[3];
    const float* Wq         = (const float*)d_in[4];
    const float* Wk         = (const float*)d_in[5];
    const float* w_v        = (const float*)d_in[6];
    float* out = (float*)d_out;

    float*  qf    = (float*)d_ws;                          // 1 MB f32 (pre-scaled)
    ushort* kfeat = (ushort*)(qf + (size_t)BB*QQ*HH);      // 4 MB bf16 (pre-scaled)
    ushort* v16   = kfeat + (size_t)BB*KK*HH;              // 4 MB bf16 values
    float*  pm    = (float*)(v16 + (size_t)BB*KK*DD);      // 16 KB
    float*  pl    = pm + BB*QQ*NZ;                         // 16 KB
    float*  po    = pl + BB*QQ*NZ;                         // 4 MB

    proj_both<<<dim3(176, HH/64), 256, 0, stream>>>(
        querys, Wq, qf, keys, Wk, kfeat, values, v16, valid_lens);
    fused_flash<<<dim3(PERSIST), 512, 0, stream>>>(
        qf, kfeat, w_v, valid_lens, v16, pm, pl, po);
    combine_kernel<<<dim3(BB, QQ), 256, 0, stream>>>(
        pm, pl, po, valid_lens, out);
}

// Round 12
// 58.001 us; speedup vs baseline: 1.1572x; 1.0682x over previous
//
#include <hip/hip_runtime.h>

#define BB 16
#define QQ 64
#define KK 512
#define DD 256
#define HH 256
#define KTILE 128
#define NZ 4
#define PERSIST 2048

#define LOG2E2 2.88539008177792681f   // 2*log2(e): exp2(LOG2E2*x) = e^{2x}

typedef unsigned int uint;
typedef unsigned short ushort;

__device__ __forceinline__ float fast_exp2(float x) {
#if __has_builtin(__builtin_amdgcn_exp2f)
    return __builtin_amdgcn_exp2f(x);
#else
    return exp2f(x);
#endif
}

__device__ __forceinline__ ushort f32_to_bf16_rtne(float x) {
    uint u = __float_as_uint(x);
    u = (u + 0x7FFFu + ((u >> 16) & 1u)) >> 16;
    return (ushort)u;
}

// unpack 8 bf16 (uint4) -> two float4
__device__ __forceinline__ void cvt8(uint4 u, float4& a, float4& b) {
    a.x = __uint_as_float(u.x << 16); a.y = __uint_as_float(u.x & 0xFFFF0000u);
    a.z = __uint_as_float(u.y << 16); a.w = __uint_as_float(u.y & 0xFFFF0000u);
    b.x = __uint_as_float(u.z << 16); b.y = __uint_as_float(u.z & 0xFFFF0000u);
    b.z = __uint_as_float(u.w << 16); b.w = __uint_as_float(u.w & 0xFFFF0000u);
}

// ---------------------------------------------------------------------------
// Both projections, one launch (R9-verified version). q-features -> f32
// (1MB); k-features -> bf16 (4MB). Both pre-scaled by 2log2e. Fully-masked
// key tiles skipped. NO V conversion (the 32-block convert tail cost more
// than bf16-V saved).
// ---------------------------------------------------------------------------
__global__ __launch_bounds__(256) void proj_both(
        const float* __restrict__ Xq, const float* __restrict__ Wq, float* __restrict__ Yq,
        const float* __restrict__ Xk, const float* __restrict__ Wk, ushort* __restrict__ Yk16,
        const int* __restrict__ valid_lens) {
    __shared__ float XsT[32][68];
    __shared__ float Ws[32][64];
    const int rt = blockIdx.x;
    const bool is_q = (rt < 16);
    const float* X; const float* W; int row0;
    if (is_q) { X = Xq; W = Wq; row0 = rt * 64; }
    else {
        X = Xk; W = Wk; row0 = (rt - 16) * 64;
        const int bb    = row0 >> 9;
        const int local = row0 & 511;
        if (local >= valid_lens[bb]) return;
    }
    const int col0 = blockIdx.y * 64;
    const int tid = threadIdx.x;
    const int tx = tid & 15, ty = tid >> 4;

    float acc[4][4] = {};

    for (int k0 = 0; k0 < HH; k0 += 32) {
        {
            const int m  = tid >> 3;
            const int kk = (tid & 7) * 4;
            #pragma unroll
            for (int s = 0; s < 2; ++s) {
                float4 x4 = *(const float4*)(X + (size_t)(row0 + m + 32*s) * HH + k0 + kk);
                XsT[kk+0][m+32*s] = x4.x;
                XsT[kk+1][m+32*s] = x4.y;
                XsT[kk+2][m+32*s] = x4.z;
                XsT[kk+3][m+32*s] = x4.w;
            }
        }
        {
            const int kk = tid >> 4;
            const int c  = (tid & 15) * 4;
            #pragma unroll
            for (int s = 0; s < 2; ++s) {
                float4 w4 = *(const float4*)(W + (size_t)(k0 + kk + 16*s) * HH + col0 + c);
                *(float4*)(&Ws[kk+16*s][c]) = w4;
            }
        }
        __syncthreads();
        #pragma unroll
        for (int kk = 0; kk < 32; ++kk) {
            float4 a = *(const float4*)(&XsT[kk][ty*4]);
            float4 b = *(const float4*)(&Ws[kk][tx*4]);
            acc[0][0] += a.x*b.x; acc[0][1] += a.x*b.y; acc[0][2] += a.x*b.z; acc[0][3] += a.x*b.w;
            acc[1][0] += a.y*b.x; acc[1][1] += a.y*b.y; acc[1][2] += a.y*b.z; acc[1][3] += a.y*b.w;
            acc[2][0] += a.z*b.x; acc[2][1] += a.z*b.y; acc[2][2] += a.z*b.z; acc[2][3] += a.z*b.w;
            acc[3][0] += a.w*b.x; acc[3][1] += a.w*b.y; acc[3][2] += a.w*b.z; acc[3][3] += a.w*b.w;
        }
        __syncthreads();
    }
    if (is_q) {
        #pragma unroll
        for (int i = 0; i < 4; ++i) {
            float4 o = make_float4(acc[i][0]*LOG2E2, acc[i][1]*LOG2E2,
                                   acc[i][2]*LOG2E2, acc[i][3]*LOG2E2);
            *(float4*)(Yq + (size_t)(row0 + ty*4 + i) * HH + col0 + tx*4) = o;
        }
    } else {
        #pragma unroll
        for (int i = 0; i < 4; ++i) {
            ushort4 o;
            o.x = f32_to_bf16_rtne(acc[i][0]*LOG2E2);
            o.y = f32_to_bf16_rtne(acc[i][1]*LOG2E2);
            o.z = f32_to_bf16_rtne(acc[i][2]*LOG2E2);
            o.w = f32_to_bf16_rtne(acc[i][3]*LOG2E2);
            *(ushort4*)(Yk16 + (size_t)(row0 + ty*4 + i) * HH + col0 + tx*4) = o;
        }
    }
}

// ---------------------------------------------------------------------------
// Persistent flash-style fused kernel, q-pair items, 2048 blocks x 256 thr
// (4 waves). Work items = (active tile) x 32 q-pairs via prefix scan of
// ceil(vl/128); block owns a contiguous chunk (same-tile items adjacent ->
// L2 reuse of the tile's K/V). Per item: 4 waves x 32-k strips, scores for
// both q (K loads amortized 2x), per-row softmax stats, PV partial with
// f32 V (amortized 2x).
// ---------------------------------------------------------------------------
__global__ __launch_bounds__(256) void fused_flash(
        const float* __restrict__ qf, const ushort* __restrict__ kf16,
        const float* __restrict__ w_v, const int* __restrict__ valid_lens,
        const float* __restrict__ values,
        float* __restrict__ pm, float* __restrict__ pl, float* __restrict__ po) {
    __shared__ float sc[2][KTILE];      // 1 KB scores
    __shared__ float pp[2][KTILE];      // 1 KB unnormalized probs
    __shared__ float red[4][2][DD];     // 8 KB PV partials

    const int tid  = threadIdx.x;
    const int lane = tid & 63;
    const int w    = tid >> 6;          // 0..3
    const int hg   = lane & 15;
    const int ksub = lane >> 4;
    const int h0   = hg * 16;

    float4 nw[4];
    float wvsum = 0.f;
    #pragma unroll
    for (int i = 0; i < 4; ++i) {
        float4 wv4 = *(const float4*)(w_v + h0 + i*4);
        wvsum += ((wv4.x + wv4.y) + (wv4.z + wv4.w));
        nw[i] = make_float4(-2.f*wv4.x, -2.f*wv4.y, -2.f*wv4.z, -2.f*wv4.w);
    }

    // total active tiles and this block's contiguous item chunk
    int TT = 0;
    #pragma unroll
    for (int i = 0; i < BB; ++i)
        TT += (valid_lens[i] + KTILE - 1) >> 7;
    const int items = TT * 32;                   // q-pair items
    const int qch   = items >> 11;               // items / 2048
    const int rch   = items & 2047;
    const int bid   = blockIdx.x;
    const int lo_it = bid * qch + ((bid < rch) ? bid : rch);
    const int n_it  = qch + ((bid < rch) ? 1 : 0);

    for (int t = lo_it; t < lo_it + n_it; ++t) {
        const int tile_idx = t >> 5;
        const int q0       = (t & 31) * 2;

        // map tile_idx -> (b, z) via unrolled prefix scan
        int bb = 0, zz = 0, vlb = 1, acc = 0;
        #pragma unroll
        for (int i = 0; i < BB; ++i) {
            const int v   = valid_lens[i];
            const int nzi = (v + KTILE - 1) >> 7;
            const bool hit = (tile_idx >= acc) && (tile_idx < acc + nzi);
            if (hit) { bb = i; zz = tile_idx - acc; vlb = v; }
            acc += nzi;
        }

        const int tile_lo = zz * KTILE;
        const int tile_hi = (tile_lo + KTILE < vlb) ? (tile_lo + KTILE) : vlb;

        sc[tid >> 7][tid & 127] = -1e6f;        // 256 thr cover 2x128

        float4 qA[4], qB[4];
        {
            const float* qrA = qf + (size_t)(bb*QQ + q0) * HH + h0;
            const float* qrB = qrA + HH;
            #pragma unroll
            for (int i = 0; i < 4; ++i) {
                qA[i] = *(const float4*)(qrA + i*4);
                qB[i] = *(const float4*)(qrB + i*4);
            }
        }

        // wave strip: 32 k
        const int lo  = tile_lo + w * 32;
        int hi = lo + 32; hi = (hi > tile_hi) ? tile_hi : hi;
        const int cnt = hi - lo;
        const int ng  = (cnt <= 0) ? 0 : ((cnt + 3) >> 2);

        __syncthreads();   // sc init visible; prev item consumed

        // ---- Phase A: scores for both q over the strip ----
        {
            const size_t brows = (size_t)bb * KK;
            uint4 c0, c1;
            if (ng > 0) {
                int row = lo + ksub;
                row = (row < tile_hi) ? row : (tile_hi - 1);
                const ushort* p = kf16 + (brows + row) * HH + h0;
                c0 = *(const uint4*)(p);
                c1 = *(const uint4*)(p + 8);
            }
            for (int g = 0; g < ng; ++g) {
                uint4 n0, n1;
                const bool more = (g + 1 < ng);
                if (more) {
                    int row = lo + (g+1)*4 + ksub;
                    row = (row < tile_hi) ? row : (tile_hi - 1);
                    const ushort* p = kf16 + (brows + row) * HH + h0;
                    n0 = *(const uint4*)(p);
                    n1 = *(const uint4*)(p + 8);
                }
                float4 kv[4];
                cvt8(c0, kv[0], kv[1]);
                cvt8(c1, kv[2], kv[3]);

                float a0 = wvsum, a1 = 0.f, a2 = 0.f, a3 = 0.f;
                float b0 = wvsum, b1 = 0.f, b2 = 0.f, b3 = 0.f;
                #pragma unroll
                for (int i = 0; i < 4; ++i) {
                    float eA0 = fast_exp2(qA[i].x + kv[i].x);
                    float eA1 = fast_exp2(qA[i].y + kv[i].y);
                    float eA2 = fast_exp2(qA[i].z + kv[i].z);
                    float eA3 = fast_exp2(qA[i].w + kv[i].w);
                    a0 = fmaf(nw[i].x, __builtin_amdgcn_rcpf(eA0 + 1.f), a0);
                    a1 = fmaf(nw[i].y, __builtin_amdgcn_rcpf(eA1 + 1.f), a1);
                    a2 = fmaf(nw[i].z, __builtin_amdgcn_rcpf(eA2 + 1.f), a2);
                    a3 = fmaf(nw[i].w, __builtin_amdgcn_rcpf(eA3 + 1.f), a3);
                    float eB0 = fast_exp2(qB[i].x + kv[i].x);
                    float eB1 = fast_exp2(qB[i].y + kv[i].y);
                    float eB2 = fast_exp2(qB[i].z + kv[i].z);
                    float eB3 = fast_exp2(qB[i].w + kv[i].w);
                    b0 = fmaf(nw[i].x, __builtin_amdgcn_rcpf(eB0 + 1.f), b0);
                    b1 = fmaf(nw[i].y, __builtin_amdgcn_rcpf(eB1 + 1.f), b1);
                    b2 = fmaf(nw[i].z, __builtin_amdgcn_rcpf(eB2 + 1.f), b2);
                    b3 = fmaf(nw[i].w, __builtin_amdgcn_rcpf(eB3 + 1.f), b3);
                }
                float sA = (a0 + a1) + (a2 + a3);
                float sB = (b0 + b1) + (b2 + b3);
                #pragma unroll
                for (int off = 8; off; off >>= 1) {
                    sA += __shfl_xor(sA, off);
                    sB += __shfl_xor(sB, off);
                }
                const int k = lo + g*4 + ksub;
                if (hg == 0 && k < hi) {
                    sc[0][k - tile_lo] = sA;
                    sc[1][k - tile_lo] = sB;
                }
                if (more) { c0 = n0; c1 = n1; }
            }
        }
        __syncthreads();

        // ---- Phase B: per-row tile max/sum + unnormalized p (waves 0,1) ----
        if (w < 2) {
            float s0 = sc[w][lane*2], s1 = sc[w][lane*2 + 1];
            float m = fmaxf(s0, s1);
            #pragma unroll
            for (int off = 32; off; off >>= 1) m = fmaxf(m, __shfl_xor(m, off));
            float p0 = __expf(s0 - m), p1 = __expf(s1 - m);
            float l = p0 + p1;
            #pragma unroll
            for (int off = 32; off; off >>= 1) l += __shfl_xor(l, off);
            pp[w][lane*2]     = p0;
            pp[w][lane*2 + 1] = p1;
            if (lane == 0) {
                const int id = ((bb*QQ + q0 + w) << 2) + zz;
                pm[id] = m; pl[id] = l;
            }
        }
        __syncthreads();

        // ---- Phase C: PV partial over the strip, f32 V, both q ----
        {
            const float* V = values + (size_t)bb * KK * DD + lane*4;
            float4 aA = make_float4(0.f,0.f,0.f,0.f);
            float4 aB = aA;
            #pragma unroll 4
            for (int k = lo; k < hi; ++k) {
                const float pA = pp[0][k - tile_lo];
                const float pB = pp[1][k - tile_lo];
                float4 v4 = *(const float4*)(V + (size_t)k * DD);
                aA.x = fmaf(pA, v4.x, aA.x); aA.y = fmaf(pA, v4.y, aA.y);
                aA.z = fmaf(pA, v4.z, aA.z); aA.w = fmaf(pA, v4.w, aA.w);
                aB.x = fmaf(pB, v4.x, aB.x); aB.y = fmaf(pB, v4.y, aB.y);
                aB.z = fmaf(pB, v4.z, aB.z); aB.w = fmaf(pB, v4.w, aB.w);
            }
            *(float4*)(&red[w][0][lane*4]) = aA;
            *(float4*)(&red[w][1][lane*4]) = aB;
        }
        __syncthreads();

        // ---- write PV partials: 256 thr x 2 rounds = 2 q x 256 d ----
        #pragma unroll
        for (int i = 0; i < 2; ++i) {
            const int idx = tid + i*256;
            const int qq = idx >> 8, d = idx & 255;
            const float o = (red[0][qq][d] + red[1][qq][d])
                          + (red[2][qq][d] + red[3][qq][d]);
            po[(size_t)(((bb*QQ + q0 + qq) << 2) + zz) * DD + d] = o;
        }
        __syncthreads();
    }
}

// ---------------------------------------------------------------------------
// Combine <=4 tile partials per (b,q): online-softmax merge. grid (B,Q), 256.
// ---------------------------------------------------------------------------
__global__ __launch_bounds__(256) void combine_kernel(
        const float* __restrict__ pm, const float* __restrict__ pl,
        const float* __restrict__ po, const int* __restrict__ valid_lens,
        float* __restrict__ out) {
    const int b   = blockIdx.x;
    const int q   = blockIdx.y;
    const int tid = threadIdx.x;
    const int vl  = valid_lens[b];
    const int nz  = (vl + KTILE - 1) >> 7;
    const int idx4 = (b*QQ + q) << 2;

    float mz[NZ], wz[NZ];
    float M = -3.0e38f;
    #pragma unroll
    for (int z = 0; z < NZ; ++z) {
        mz[z] = (z < nz) ? pm[idx4 + z] : -3.0e38f;
        M = fmaxf(M, mz[z]);
    }
    float L = 0.f;
    #pragma unroll
    for (int z = 0; z < NZ; ++z) {
        wz[z] = (z < nz) ? __expf(mz[z] - M) : 0.f;
        L = fmaf(wz[z], (z < nz) ? pl[idx4 + z] : 0.f, L);
    }
    const float inv = 1.f / L;

    float o = 0.f;
    #pragma unroll
    for (int z = 0; z < NZ; ++z) {
        if (z < nz)
            o = fmaf(wz[z], po[(size_t)(idx4 + z) * DD + tid], o);
    }
    out[(size_t)(b*QQ + q) * DD + tid] = o * inv;
}

extern "C" void kernel_launch(void* const* d_in, const int* in_sizes, int n_in,
                              void* d_out, int out_size, void* d_ws, size_t ws_size,
                              hipStream_t stream) {
    (void)in_sizes; (void)n_in; (void)out_size; (void)ws_size;
    const float* querys     = (const float*)d_in[0];
    const float* keys       = (const float*)d_in[1];
    const float* values     = (const float*)d_in[2];
    const int*   valid_lens = (const int*)d_in[3];
    const float* Wq         = (const float*)d_in[4];
    const float* Wk         = (const float*)d_in[5];
    const float* w_v        = (const float*)d_in[6];
    float* out = (float*)d_out;

    float*  qf    = (float*)d_ws;                          // 1 MB f32 (pre-scaled)
    ushort* kfeat = (ushort*)(qf + (size_t)BB*QQ*HH);      // 4 MB bf16 (pre-scaled)
    float*  pm    = (float*)(kfeat + (size_t)BB*KK*HH);    // 16 KB
    float*  pl    = pm + BB*QQ*NZ;                         // 16 KB
    float*  po    = pl + BB*QQ*NZ;                         // 4 MB

    proj_both<<<dim3(16 + BB*KK/64, HH/64), 256, 0, stream>>>(
        querys, Wq, qf, keys, Wk, kfeat, valid_lens);
    fused_flash<<<dim3(PERSIST), 256, 0, stream>>>(
        qf, kfeat, w_v, valid_lens, values, pm, pl, po);
    combine_kernel<<<dim3(BB, QQ), 256, 0, stream>>>(
        pm, pl, po, valid_lens, out);
}

// Round 13
// 44.241 us; speedup vs baseline: 1.5171x; 1.3110x over previous
//
#include <hip/hip_runtime.h>

#define BB 16
#define QQ 64
#define KK 512
#define DD 256
#define HH 256
#define KTILE 128
#define NZ 4
#define PERSIST 2048
#define LDST 56   // LDS row stride (bf16 elems): 112B, 16B-aligned, ~2-way banks

#define LOG2E2 2.88539008177792681f   // 2*log2(e): exp2(LOG2E2*x) = e^{2x}

typedef unsigned int uint;
typedef unsigned short ushort;
typedef __attribute__((ext_vector_type(8))) short bf16x8;
typedef __attribute__((ext_vector_type(8))) unsigned short ushort8;
typedef __attribute__((ext_vector_type(4))) float f32x4;

__device__ __forceinline__ float fast_exp2(float x) {
#if __has_builtin(__builtin_amdgcn_exp2f)
    return __builtin_amdgcn_exp2f(x);
#else
    return exp2f(x);
#endif
}

__device__ __forceinline__ ushort f32_to_bf16_rtne(float x) {
    uint u = __float_as_uint(x);
    u = (u + 0x7FFFu + ((u >> 16) & 1u)) >> 16;
    return (ushort)u;
}

// unpack 8 bf16 (uint4) -> two float4
__device__ __forceinline__ void cvt8(uint4 u, float4& a, float4& b) {
    a.x = __uint_as_float(u.x << 16); a.y = __uint_as_float(u.x & 0xFFFF0000u);
    a.z = __uint_as_float(u.y << 16); a.w = __uint_as_float(u.y & 0xFFFF0000u);
    b.x = __uint_as_float(u.z << 16); b.y = __uint_as_float(u.z & 0xFFFF0000u);
    b.z = __uint_as_float(u.w << 16); b.w = __uint_as_float(u.w & 0xFFFF0000u);
}

// ---------------------------------------------------------------------------
// MFMA bf16 projections. Y = (X @ W) * 2log2e. 64x64 tile / block, 4 waves,
// wave w computes rows [w*16, w*16+16) x all 64 cols (4 16x16 tiles).
// A staged row-major bf16 [64][LDST]; B staged TRANSPOSED bf16 [64][LDST]
// (Bt[col][k]) so both fragments are contiguous-8 b128 reads.
// Fragments (mfma_f32_16x16x32_bf16): A row=lane&15, k=(lane>>4)*8+i;
// B col=lane&15, k=(lane>>4)*8+i; D col=lane&15, row=(lane>>4)*4+j.
// q-features -> f32 (1MB); k-features -> bf16 (4MB); masked key tiles skip.
// ---------------------------------------------------------------------------
__global__ __launch_bounds__(256) void proj_both(
        const float* __restrict__ Xq, const float* __restrict__ Wq, float* __restrict__ Yq,
        const float* __restrict__ Xk, const float* __restrict__ Wk, ushort* __restrict__ Yk16,
        const int* __restrict__ valid_lens) {
    __shared__ ushort As[64 * LDST];   // 7 KB
    __shared__ ushort Bt[64 * LDST];   // 7 KB
    const int rt = blockIdx.x;
    const bool is_q = (rt < 16);
    const float* X; const float* W; int row0;
    if (is_q) { X = Xq; W = Wq; row0 = rt * 64; }
    else {
        X = Xk; W = Wk; row0 = (rt - 16) * 64;
        const int bb    = row0 >> 9;
        const int local = row0 & 511;
        if (local >= valid_lens[bb]) return;
    }
    const int col0 = blockIdx.y * 64;
    const int tid  = threadIdx.x;
    const int lane = tid & 63;
    const int w    = tid >> 6;

    f32x4 acc[4] = {{0.f,0.f,0.f,0.f}, {0.f,0.f,0.f,0.f},
                    {0.f,0.f,0.f,0.f}, {0.f,0.f,0.f,0.f}};

    // staging indices
    const int ar = tid >> 2;            // A: row 0..63
    const int ak = (tid & 3) * 8;       // A: k chunk of 8
    const int bc = tid & 15;            // B: col group (4 cols)
    const int bk = tid >> 4;            // B: k row 0..15 (x2 halves)

    for (int k0 = 0; k0 < HH; k0 += 32) {
        {   // stage A: X[row0+ar][k0+ak .. +7] -> bf16 As[ar][ak]
            const float* xp = X + (size_t)(row0 + ar) * HH + k0 + ak;
            float4 x0 = *(const float4*)(xp);
            float4 x1 = *(const float4*)(xp + 4);
            ushort8 o;
            o[0] = f32_to_bf16_rtne(x0.x); o[1] = f32_to_bf16_rtne(x0.y);
            o[2] = f32_to_bf16_rtne(x0.z); o[3] = f32_to_bf16_rtne(x0.w);
            o[4] = f32_to_bf16_rtne(x1.x); o[5] = f32_to_bf16_rtne(x1.y);
            o[6] = f32_to_bf16_rtne(x1.z); o[7] = f32_to_bf16_rtne(x1.w);
            *(ushort8*)(&As[ar * LDST + ak]) = o;
        }
        {   // stage Bt: W[k0+bk(+16)][col0+bc*4 ..+3] -> Bt[bc*4+j][bk(+16)]
            #pragma unroll
            for (int s = 0; s < 2; ++s) {
                float4 wv = *(const float4*)(W + (size_t)(k0 + bk + 16*s) * HH + col0 + bc*4);
                Bt[(bc*4 + 0) * LDST + bk + 16*s] = f32_to_bf16_rtne(wv.x);
                Bt[(bc*4 + 1) * LDST + bk + 16*s] = f32_to_bf16_rtne(wv.y);
                Bt[(bc*4 + 2) * LDST + bk + 16*s] = f32_to_bf16_rtne(wv.z);
                Bt[(bc*4 + 3) * LDST + bk + 16*s] = f32_to_bf16_rtne(wv.w);
            }
        }
        __syncthreads();

        const bf16x8 af = *(const bf16x8*)(&As[(w*16 + (lane & 15)) * LDST + (lane >> 4) * 8]);
        #pragma unroll
        for (int ct = 0; ct < 4; ++ct) {
            const bf16x8 bf = *(const bf16x8*)(&Bt[(ct*16 + (lane & 15)) * LDST + (lane >> 4) * 8]);
            acc[ct] = __builtin_amdgcn_mfma_f32_16x16x32_bf16(af, bf, acc[ct], 0, 0, 0);
        }
        __syncthreads();
    }

    // epilogue: D col=lane&15, row=(lane>>4)*4+j ; wave rows at w*16
    const int orow = row0 + w*16 + (lane >> 4) * 4;
    const int ocol = col0 + (lane & 15);
    if (is_q) {
        #pragma unroll
        for (int ct = 0; ct < 4; ++ct)
            #pragma unroll
            for (int j = 0; j < 4; ++j)
                Yq[(size_t)(orow + j) * HH + ocol + ct*16] = acc[ct][j] * LOG2E2;
    } else {
        #pragma unroll
        for (int ct = 0; ct < 4; ++ct)
            #pragma unroll
            for (int j = 0; j < 4; ++j)
                Yk16[(size_t)(orow + j) * HH + ocol + ct*16] =
                    f32_to_bf16_rtne(acc[ct][j] * LOG2E2);
    }
}

// ---------------------------------------------------------------------------
// Persistent flash-style fused kernel, q-pair items (R12-identical).
// ---------------------------------------------------------------------------
__global__ __launch_bounds__(256) void fused_flash(
        const float* __restrict__ qf, const ushort* __restrict__ kf16,
        const float* __restrict__ w_v, const int* __restrict__ valid_lens,
        const float* __restrict__ values,
        float* __restrict__ pm, float* __restrict__ pl, float* __restrict__ po) {
    __shared__ float sc[2][KTILE];
    __shared__ float pp[2][KTILE];
    __shared__ float red[4][2][DD];

    const int tid  = threadIdx.x;
    const int lane = tid & 63;
    const int w    = tid >> 6;
    const int hg   = lane & 15;
    const int ksub = lane >> 4;
    const int h0   = hg * 16;

    float4 nw[4];
    float wvsum = 0.f;
    #pragma unroll
    for (int i = 0; i < 4; ++i) {
        float4 wv4 = *(const float4*)(w_v + h0 + i*4);
        wvsum += ((wv4.x + wv4.y) + (wv4.z + wv4.w));
        nw[i] = make_float4(-2.f*wv4.x, -2.f*wv4.y, -2.f*wv4.z, -2.f*wv4.w);
    }

    int TT = 0;
    #pragma unroll
    for (int i = 0; i < BB; ++i)
        TT += (valid_lens[i] + KTILE - 1) >> 7;
    const int items = TT * 32;
    const int qch   = items >> 11;
    const int rch   = items & 2047;
    const int bid   = blockIdx.x;
    const int lo_it = bid * qch + ((bid < rch) ? bid : rch);
    const int n_it  = qch + ((bid < rch) ? 1 : 0);

    for (int t = lo_it; t < lo_it + n_it; ++t) {
        const int tile_idx = t >> 5;
        const int q0       = (t & 31) * 2;

        int bb = 0, zz = 0, vlb = 1, acc = 0;
        #pragma unroll
        for (int i = 0; i < BB; ++i) {
            const int v   = valid_lens[i];
            const int nzi = (v + KTILE - 1) >> 7;
            const bool hit = (tile_idx >= acc) && (tile_idx < acc + nzi);
            if (hit) { bb = i; zz = tile_idx - acc; vlb = v; }
            acc += nzi;
        }

        const int tile_lo = zz * KTILE;
        const int tile_hi = (tile_lo + KTILE < vlb) ? (tile_lo + KTILE) : vlb;

        sc[tid >> 7][tid & 127] = -1e6f;

        float4 qA[4], qB[4];
        {
            const float* qrA = qf + (size_t)(bb*QQ + q0) * HH + h0;
            const float* qrB = qrA + HH;
            #pragma unroll
            for (int i = 0; i < 4; ++i) {
                qA[i] = *(const float4*)(qrA + i*4);
                qB[i] = *(const float4*)(qrB + i*4);
            }
        }

        const int lo  = tile_lo + w * 32;
        int hi = lo + 32; hi = (hi > tile_hi) ? tile_hi : hi;
        const int cnt = hi - lo;
        const int ng  = (cnt <= 0) ? 0 : ((cnt + 3) >> 2);

        __syncthreads();

        {   // Phase A: scores for both q
            const size_t brows = (size_t)bb * KK;
            uint4 c0, c1;
            if (ng > 0) {
                int row = lo + ksub;
                row = (row < tile_hi) ? row : (tile_hi - 1);
                const ushort* p = kf16 + (brows + row) * HH + h0;
                c0 = *(const uint4*)(p);
                c1 = *(const uint4*)(p + 8);
            }
            for (int g = 0; g < ng; ++g) {
                uint4 n0, n1;
                const bool more = (g + 1 < ng);
                if (more) {
                    int row = lo + (g+1)*4 + ksub;
                    row = (row < tile_hi) ? row : (tile_hi - 1);
                    const ushort* p = kf16 + (brows + row) * HH + h0;
                    n0 = *(const uint4*)(p);
                    n1 = *(const uint4*)(p + 8);
                }
                float4 kv[4];
                cvt8(c0, kv[0], kv[1]);
                cvt8(c1, kv[2], kv[3]);

                float a0 = wvsum, a1 = 0.f, a2 = 0.f, a3 = 0.f;
                float b0 = wvsum, b1 = 0.f, b2 = 0.f, b3 = 0.f;
                #pragma unroll
                for (int i = 0; i < 4; ++i) {
                    float eA0 = fast_exp2(qA[i].x + kv[i].x);
                    float eA1 = fast_exp2(qA[i].y + kv[i].y);
                    float eA2 = fast_exp2(qA[i].z + kv[i].z);
                    float eA3 = fast_exp2(qA[i].w + kv[i].w);
                    a0 = fmaf(nw[i].x, __builtin_amdgcn_rcpf(eA0 + 1.f), a0);
                    a1 = fmaf(nw[i].y, __builtin_amdgcn_rcpf(eA1 + 1.f), a1);
                    a2 = fmaf(nw[i].z, __builtin_amdgcn_rcpf(eA2 + 1.f), a2);
                    a3 = fmaf(nw[i].w, __builtin_amdgcn_rcpf(eA3 + 1.f), a3);
                    float eB0 = fast_exp2(qB[i].x + kv[i].x);
                    float eB1 = fast_exp2(qB[i].y + kv[i].y);
                    float eB2 = fast_exp2(qB[i].z + kv[i].z);
                    float eB3 = fast_exp2(qB[i].w + kv[i].w);
                    b0 = fmaf(nw[i].x, __builtin_amdgcn_rcpf(eB0 + 1.f), b0);
                    b1 = fmaf(nw[i].y, __builtin_amdgcn_rcpf(eB1 + 1.f), b1);
                    b2 = fmaf(nw[i].z, __builtin_amdgcn_rcpf(eB2 + 1.f), b2);
                    b3 = fmaf(nw[i].w, __builtin_amdgcn_rcpf(eB3 + 1.f), b3);
                }
                float sA = (a0 + a1) + (a2 + a3);
                float sB = (b0 + b1) + (b2 + b3);
                #pragma unroll
                for (int off = 8; off; off >>= 1) {
                    sA += __shfl_xor(sA, off);
                    sB += __shfl_xor(sB, off);
                }
                const int k = lo + g*4 + ksub;
                if (hg == 0 && k < hi) {
                    sc[0][k - tile_lo] = sA;
                    sc[1][k - tile_lo] = sB;
                }
                if (more) { c0 = n0; c1 = n1; }
            }
        }
        __syncthreads();

        if (w < 2) {   // Phase B
            float s0 = sc[w][lane*2], s1 = sc[w][lane*2 + 1];
            float m = fmaxf(s0, s1);
            #pragma unroll
            for (int off = 32; off; off >>= 1) m = fmaxf(m, __shfl_xor(m, off));
            float p0 = __expf(s0 - m), p1 = __expf(s1 - m);
            float l = p0 + p1;
            #pragma unroll
            for (int off = 32; off; off >>= 1) l += __shfl_xor(l, off);
            pp[w][lane*2]     = p0;
            pp[w][lane*2 + 1] = p1;
            if (lane == 0) {
                const int id = ((bb*QQ + q0 + w) << 2) + zz;
                pm[id] = m; pl[id] = l;
            }
        }
        __syncthreads();

        {   // Phase C: PV partial, f32 V, both q
            const float* V = values + (size_t)bb * KK * DD + lane*4;
            float4 aA = make_float4(0.f,0.f,0.f,0.f);
            float4 aB = aA;
            #pragma unroll 4
            for (int k = lo; k < hi; ++k) {
                const float pA = pp[0][k - tile_lo];
                const float pB = pp[1][k - tile_lo];
                float4 v4 = *(const float4*)(V + (size_t)k * DD);
                aA.x = fmaf(pA, v4.x, aA.x); aA.y = fmaf(pA, v4.y, aA.y);
                aA.z = fmaf(pA, v4.z, aA.z); aA.w = fmaf(pA, v4.w, aA.w);
                aB.x = fmaf(pB, v4.x, aB.x); aB.y = fmaf(pB, v4.y, aB.y);
                aB.z = fmaf(pB, v4.z, aB.z); aB.w = fmaf(pB, v4.w, aB.w);
            }
            *(float4*)(&red[w][0][lane*4]) = aA;
            *(float4*)(&red[w][1][lane*4]) = aB;
        }
        __syncthreads();

        #pragma unroll
        for (int i = 0; i < 2; ++i) {
            const int idx = tid + i*256;
            const int qq = idx >> 8, d = idx & 255;
            const float o = (red[0][qq][d] + red[1][qq][d])
                          + (red[2][qq][d] + red[3][qq][d]);
            po[(size_t)(((bb*QQ + q0 + qq) << 2) + zz) * DD + d] = o;
        }
        __syncthreads();
    }
}

// ---------------------------------------------------------------------------
// Combine <=4 tile partials per (b,q): online-softmax merge. grid (B,Q), 256.
// ---------------------------------------------------------------------------
__global__ __launch_bounds__(256) void combine_kernel(
        const float* __restrict__ pm, const float* __restrict__ pl,
        const float* __restrict__ po, const int* __restrict__ valid_lens,
        float* __restrict__ out) {
    const int b   = blockIdx.x;
    const int q   = blockIdx.y;
    const int tid = threadIdx.x;
    const int vl  = valid_lens[b];
    const int nz  = (vl + KTILE - 1) >> 7;
    const int idx4 = (b*QQ + q) << 2;

    float mz[NZ], wz[NZ];
    float M = -3.0e38f;
    #pragma unroll
    for (int z = 0; z < NZ; ++z) {
        mz[z] = (z < nz) ? pm[idx4 + z] : -3.0e38f;
        M = fmaxf(M, mz[z]);
    }
    float L = 0.f;
    #pragma unroll
    for (int z = 0; z < NZ; ++z) {
        wz[z] = (z < nz) ? __expf(mz[z] - M) : 0.f;
        L = fmaf(wz[z], (z < nz) ? pl[idx4 + z] : 0.f, L);
    }
    const float inv = 1.f / L;

    float o = 0.f;
    #pragma unroll
    for (int z = 0; z < NZ; ++z) {
        if (z < nz)
            o = fmaf(wz[z], po[(size_t)(idx4 + z) * DD + tid], o);
    }
    out[(size_t)(b*QQ + q) * DD + tid] = o * inv;
}

extern "C" void kernel_launch(void* const* d_in, const int* in_sizes, int n_in,
                              void* d_out, int out_size, void* d_ws, size_t ws_size,
                              hipStream_t stream) {
    (void)in_sizes; (void)n_in; (void)out_size; (void)ws_size;
    const float* querys     = (const float*)d_in[0];
    const float* keys       = (const float*)d_in[1];
    const float* values     = (const float*)d_in[2];
    const int*   valid_lens = (const int*)d_in[3];
    const float* Wq         = (const float*)d_in[4];
    const float* Wk         = (const float*)d_in[5];
    const float* w_v        = (const float*)d_in[6];
    float* out = (float*)d_out;

    float*  qf    = (float*)d_ws;                          // 1 MB f32 (pre-scaled)
    ushort* kfeat = (ushort*)(qf + (size_t)BB*QQ*HH);      // 4 MB bf16 (pre-scaled)
    float*  pm    = (float*)(kfeat + (size_t)BB*KK*HH);    // 16 KB
    float*  pl    = pm + BB*QQ*NZ;                         // 16 KB
    float*  po    = pl + BB*QQ*NZ;                         // 4 MB

    proj_both<<<dim3(16 + BB*KK/64, HH/64), 256, 0, stream>>>(
        querys, Wq, qf, keys, Wk, kfeat, valid_lens);
    fused_flash<<<dim3(PERSIST), 256, 0, stream>>>(
        qf, kfeat, w_v, valid_lens, values, pm, pl, po);
    combine_kernel<<<dim3(BB, QQ), 256, 0, stream>>>(
        pm, pl, po, valid_lens, out);
}